// Round 1
// baseline (130.420 us; speedup 1.0000x reference)
//
#include <hip/hip_runtime.h>

// Problem constants (from reference): B=1024, IN=512, OUT=512, fp32.
#define B_DIM   1024
#define IN_DIM  512
#define OUT_DIM 512

// Tile config: 32x32 output tile per 256-thread block, K staged in 32-chunks.
// Grid = (1024/32) x (512/32) = 32 x 16 = 512 blocks -> 2 blocks/CU.
#define BM 32
#define BN 32
#define BK 32

// 2 / (sqrt(3) * pi^0.25)
#define MH_CONST 0.8673250691f

#if defined(__has_builtin)
#if __has_builtin(__builtin_amdgcn_exp2f)
#define FAST_EXP_NEG_HALF(sq) __builtin_amdgcn_exp2f((sq) * -0.72134752044448170368f) /* -0.5*log2(e) */
#endif
#endif
#ifndef FAST_EXP_NEG_HALF
#define FAST_EXP_NEG_HALF(sq) __expf((sq) * -0.5f)
#endif

__global__ __launch_bounds__(256) void wkan_kernel(
    const float* __restrict__ x,      // (B, IN)
    const float* __restrict__ scale,  // (OUT, IN)
    const float* __restrict__ trans,  // (OUT, IN)
    const float* __restrict__ bwgt,   // (IN, OUT)
    const float* __restrict__ wwgt,   // (OUT, IN)
    float* __restrict__ out)          // (B, OUT)
{
    // All LDS tiles transposed to [k][row], padded +2 so row stride (34 floats)
    // is even -> float2 reads are 8B-aligned; bank aliasing <=2-way (free).
    __shared__ float xs[BK][BM + 2];  // [kk][b]   : x
    __shared__ float ts[BK][BN + 2];  // [kk][o]   : translation
    __shared__ float rs[BK][BN + 2];  // [kk][o]   : 1/scale
    __shared__ float ws[BK][BN + 2];  // [kk][o]   : MH_CONST * wavelet_weight
    __shared__ float bs[BK][BN + 2];  // [kk][o]   : base_weight

    const int t  = threadIdx.x;
    const int tx = t & 15;   // -> 2 consecutive o columns
    const int ty = t >> 4;   // -> 2 consecutive b rows

    const int b0 = blockIdx.x * BM;
    const int o0 = blockIdx.y * BN;

    // Staging decomposition: 256 threads x float4 = 1024 elems = one 32x32 tile.
    const int lr = t >> 3;        // row 0..31
    const int lc = (t & 7) * 4;   // col group 0,4,...,28

    float accw[2][2] = {{0.f, 0.f}, {0.f, 0.f}};
    float accb[2][2] = {{0.f, 0.f}, {0.f, 0.f}};

    for (int k0 = 0; k0 < IN_DIM; k0 += BK) {
        // Global loads (coalesced float4 per thread per array).
        const float4 xv = *reinterpret_cast<const float4*>(&x[(b0 + lr) * IN_DIM + k0 + lc]);
        const float4 tv = *reinterpret_cast<const float4*>(&trans[(o0 + lr) * IN_DIM + k0 + lc]);
        const float4 sv = *reinterpret_cast<const float4*>(&scale[(o0 + lr) * IN_DIM + k0 + lc]);
        const float4 wv = *reinterpret_cast<const float4*>(&wwgt[(o0 + lr) * IN_DIM + k0 + lc]);
        const float4 bv = *reinterpret_cast<const float4*>(&bwgt[(k0 + lr) * OUT_DIM + o0 + lc]);

        __syncthreads();  // previous chunk's compute done before overwrite

        // Transposed scatter into LDS (4 scalar writes per array; 2-way max).
        xs[lc + 0][lr] = xv.x; xs[lc + 1][lr] = xv.y;
        xs[lc + 2][lr] = xv.z; xs[lc + 3][lr] = xv.w;

        ts[lc + 0][lr] = tv.x; ts[lc + 1][lr] = tv.y;
        ts[lc + 2][lr] = tv.z; ts[lc + 3][lr] = tv.w;

        rs[lc + 0][lr] = __frcp_rn(sv.x); rs[lc + 1][lr] = __frcp_rn(sv.y);
        rs[lc + 2][lr] = __frcp_rn(sv.z); rs[lc + 3][lr] = __frcp_rn(sv.w);

        ws[lc + 0][lr] = wv.x * MH_CONST; ws[lc + 1][lr] = wv.y * MH_CONST;
        ws[lc + 2][lr] = wv.z * MH_CONST; ws[lc + 3][lr] = wv.w * MH_CONST;

        // base_weight is (IN, OUT): row lr is already the k index.
        bs[lr][lc + 0] = bv.x; bs[lr][lc + 1] = bv.y;
        bs[lr][lc + 2] = bv.z; bs[lr][lc + 3] = bv.w;

        __syncthreads();

#pragma unroll 8
        for (int kk = 0; kk < BK; ++kk) {
            const float2 xv2 = *reinterpret_cast<const float2*>(&xs[kk][2 * ty]);
            const float2 tv2 = *reinterpret_cast<const float2*>(&ts[kk][2 * tx]);
            const float2 rv2 = *reinterpret_cast<const float2*>(&rs[kk][2 * tx]);
            const float2 wv2 = *reinterpret_cast<const float2*>(&ws[kk][2 * tx]);
            const float2 bv2 = *reinterpret_cast<const float2*>(&bs[kk][2 * tx]);

            const float xb[2] = {xv2.x, xv2.y};
            const float tr[2] = {tv2.x, tv2.y};
            const float rc[2] = {rv2.x, rv2.y};
            const float wl[2] = {wv2.x, wv2.y};
            const float bw[2] = {bv2.x, bv2.y};

#pragma unroll
            for (int oo = 0; oo < 2; ++oo) {
#pragma unroll
                for (int bb = 0; bb < 2; ++bb) {
                    const float d  = (xb[bb] - tr[oo]) * rc[oo];
                    const float sq = d * d;
                    const float e  = FAST_EXP_NEG_HALF(sq);
                    // wl*(sq-1) as one fma: wl*sq - wl
                    const float p  = fmaf(wl[oo], sq, -wl[oo]);
                    accw[bb][oo] = fmaf(p, e, accw[bb][oo]);
                    accb[bb][oo] = fmaf(xb[bb], bw[oo], accb[bb][oo]);
                }
            }
        }
    }

    // Epilogue: swish(base) + wavelet
#pragma unroll
    for (int bb = 0; bb < 2; ++bb) {
#pragma unroll
        for (int oo = 0; oo < 2; ++oo) {
            const float s   = accb[bb][oo];
            const float sig = __frcp_rn(1.0f + __expf(-s));
            out[(b0 + 2 * ty + bb) * OUT_DIM + (o0 + 2 * tx + oo)] = fmaf(s, sig, accw[bb][oo]);
        }
    }
}

extern "C" void kernel_launch(void* const* d_in, const int* in_sizes, int n_in,
                              void* d_out, int out_size, void* d_ws, size_t ws_size,
                              hipStream_t stream) {
    const float* x     = (const float*)d_in[0];  // (B, IN)
    const float* scale = (const float*)d_in[1];  // (OUT, IN)
    const float* trans = (const float*)d_in[2];  // (OUT, IN)
    const float* bwgt  = (const float*)d_in[3];  // (IN, OUT)
    const float* wwgt  = (const float*)d_in[4];  // (OUT, IN)
    float* out = (float*)d_out;                  // (B, OUT)

    dim3 grid(B_DIM / BM, OUT_DIM / BN);
    wkan_kernel<<<grid, dim3(256), 0, stream>>>(x, scale, trans, bwgt, wwgt, out);
}